// Round 6
// baseline (66.173 us; speedup 1.0000x reference)
//
#include <hip/hip_runtime.h>
#include <hip/hip_bf16.h>

typedef unsigned short u16;
typedef unsigned int u32;
typedef __attribute__((ext_vector_type(8))) short bf16x8;
typedef __attribute__((ext_vector_type(4))) float f32x4;

__device__ __forceinline__ u16 f2bf(float f) {
  return __builtin_bit_cast(u16, __float2bfloat16(f));
}

__device__ __forceinline__ bf16x8 ld_frag16(const u16* p) {
  return __builtin_bit_cast(bf16x8, *reinterpret_cast<const uint4*>(p));
}

__device__ __forceinline__ void gload_lds16(const void* g, void* l) {
  __builtin_amdgcn_global_load_lds((const __attribute__((address_space(1))) void*)g,
                                   (__attribute__((address_space(3))) void*)l, 16, 0, 0);
}

// Barrier that does NOT drain vmcnt: publish ds_writes (lgkm), fence the
// scheduler, raw s_barrier.
__device__ __forceinline__ void bar_lds() {
  asm volatile("s_waitcnt lgkmcnt(0)" ::: "memory");
  __builtin_amdgcn_sched_barrier(0);
  __builtin_amdgcn_s_barrier();
}

// ---------------------------------------------------------------------------
// Kernel 1: Y[b] = bf16( W @ X[b] )   (unchanged)
// ---------------------------------------------------------------------------
__global__ __launch_bounds__(256, 3) void gemm1(
    const float* __restrict__ x, const float* __restrict__ weight,
    u16* __restrict__ Y)
{
  constexpr int Nn = 1024, K = 256, BK = 32, SB = 40;
  __shared__ __align__(16) u16 As[128 * 32];
  __shared__ __align__(16) u16 Bs[64 * SB];

  const int t = threadIdx.x;
  const int b = blockIdx.z, mt = blockIdx.y, n0 = blockIdx.x * 64;

  const float* Wp = weight + (size_t)mt * 128 * K;
  const float* Xb = x + (size_t)b * K * Nn;

  const int w = t >> 6, l = t & 63;
  const int wm = w >> 1, wn = w & 1;
  const int lr = l & 15, lg = l >> 4;

  const int ar = t >> 1, akc = (t & 1) * 16;
  const int bm = t & 63, bkq = t >> 6;
  const float* Xcol = Xb + n0 + bm;

  f32x4 acc[4][2] = {};

  for (int kt = 0; kt < K / BK; ++kt) {
    const int k0 = kt * BK;

    float4 a4[4];
#pragma unroll
    for (int uu = 0; uu < 4; ++uu)
      a4[uu] = reinterpret_cast<const float4*>(Wp + (size_t)ar * K + k0 + akc)[uu];
    union { uint4 q[2]; u16 s[16]; } ua;
#pragma unroll
    for (int uu = 0; uu < 4; ++uu) {
      ua.s[uu * 4 + 0] = f2bf(a4[uu].x); ua.s[uu * 4 + 1] = f2bf(a4[uu].y);
      ua.s[uu * 4 + 2] = f2bf(a4[uu].z); ua.s[uu * 4 + 3] = f2bf(a4[uu].w);
    }
    {
      const int c0 = akc >> 3;
      const int sw = (ar >> 1) & 3;
      uint4* Aq = reinterpret_cast<uint4*>(As);
      Aq[ar * 4 + ((c0 + 0) ^ sw)] = ua.q[0];
      Aq[ar * 4 + ((c0 + 1) ^ sw)] = ua.q[1];
    }

    float v[8];
#pragma unroll
    for (int j = 0; j < 8; ++j)
      v[j] = Xcol[(size_t)(k0 + bkq * 8 + j) * Nn];
    union { uint4 q; u16 s[8]; } ub;
#pragma unroll
    for (int j = 0; j < 8; ++j) ub.s[j] = f2bf(v[j]);
    reinterpret_cast<uint4*>(Bs)[bm * 5 + bkq] = ub.q;

    __syncthreads();

    bf16x8 af[4], bfr[2];
#pragma unroll
    for (int mi = 0; mi < 4; ++mi) {
      const int rr = wm * 64 + mi * 16 + lr;
      const int cw = lg ^ ((rr >> 1) & 3);
      af[mi] = ld_frag16(As + rr * BK + cw * 8);
    }
#pragma unroll
    for (int ni = 0; ni < 2; ++ni) {
      const int cc = wn * 32 + ni * 16 + lr;
      bfr[ni] = ld_frag16(Bs + cc * SB + lg * 8);
    }
#pragma unroll
    for (int mi = 0; mi < 4; ++mi)
#pragma unroll
      for (int ni = 0; ni < 2; ++ni)
        acc[mi][ni] = __builtin_amdgcn_mfma_f32_16x16x32_bf16(
            af[mi], bfr[ni], acc[mi][ni], 0, 0, 0);

    __syncthreads();
  }

#pragma unroll
  for (int mi = 0; mi < 4; ++mi) {
#pragma unroll
    for (int rr = 0; rr < 4; ++rr) {
      const int row = mt * 128 + wm * 64 + mi * 16 + lg * 4 + rr;
      u16* Yrow = Y + ((size_t)(b * 256 + row)) * Nn + n0;
#pragma unroll
      for (int ni = 0; ni < 2; ++ni) {
        const int col = wn * 32 + ni * 16 + lr;
        Yrow[col] = f2bf(acc[mi][ni][rr]);
      }
    }
  }
}

// ---------------------------------------------------------------------------
// Kernel 2 (v4): out = relu(Y_slab @ adj_h + bias)
// BM=64, BN=256, BK=32. 256 blocks (4 n-tiles x 4 (h,mh) x 16 b), 512 thr
// (8 waves, 2m x 4n; per-wave out 32x64). adj read in 1 KB/row clusters.
// Same 3-deep / distance-2 / 4-buffer / raw-barrier pipeline as v3.
// B-stage: thread owns col c (t&255), k-half (t>>8): 16 strided f32 loads
// -> 2x ds_write_b128 into [n][k] SB=40 layout.
// ---------------------------------------------------------------------------
__global__ __launch_bounds__(512, 2) void gemm2(
    const float* __restrict__ adj1, const float* __restrict__ adj2,
    const u16* __restrict__ Y, const float* __restrict__ bias,
    float* __restrict__ out)
{
  constexpr int Nn = 1024, BK = 32, SB = 40, NT = Nn / BK;
  __shared__ __align__(16) u16 As[4][64 * 32];    // 4 x 4 KB
  __shared__ __align__(16) u16 Bs[4][256 * SB];   // 4 x 20 KB

  const int t = threadIdx.x;
  const int b = blockIdx.z;
  const int h = blockIdx.y >> 1, mh = blockIdx.y & 1;
  const int n0 = blockIdx.x * 256;

  const float* adj = (h == 0 ? adj1 : adj2) + (size_t)b * Nn * Nn;
  const u16* Yb = Y + ((size_t)(b * 256 + h * 128 + mh * 64)) * Nn;  // [64][1024]

  const int w = t >> 6, l = t & 63;
  const int wm = w & 1, wn = w >> 1;          // 2 m-halves x 4 n-groups
  const int lr = l & 15, lg = l >> 4;

  // A-staging: 256 chunks of 16 B; waves 0-3 only (t<256), chunk = t.
  const int a_r = t >> 2, a_c = t & 3;
  const int a_cg = a_c ^ ((a_r >> 1) & 3);
  const u16* a_src = Yb + (size_t)a_r * Nn + a_cg * 8;   // + tt*BK at use
  const int a_dstoff = (w * 64) * 8;                      // u16 elements

  // B-staging: col bc = t&255, k-half bh = t>>8 (16 k's each).
  const int bc = t & 255, bh = t >> 8;
  const float* adjcol = adj + n0 + bc;
  const int b_dstoff = bc * SB + bh * 16;                 // u16 elements

  f32x4 acc[2][4] = {};

  auto ISSUE_A = [&](int tt) {
    if (t < 256)
      gload_lds16(a_src + tt * BK, (void*)(&As[tt & 3][0] + a_dstoff));
  };
  auto LOAD_B = [&](int tt, float* v) {
#pragma unroll
    for (int j = 0; j < 16; ++j)
      v[j] = adjcol[(size_t)(tt * BK + bh * 16 + j) * Nn];
  };
  auto WRITE_B = [&](int tt, const float* v) {
    union { uint4 q[2]; u16 s[16]; } ub;
#pragma unroll
    for (int j = 0; j < 16; ++j) ub.s[j] = f2bf(v[j]);
    uint4* dst = reinterpret_cast<uint4*>(&Bs[tt & 3][0] + b_dstoff);
    dst[0] = ub.q[0];
    dst[1] = ub.q[1];
  };
  auto COMPUTE = [&](int tt) {
    const u16* Ab = &As[tt & 3][0];
    const u16* Bb = &Bs[tt & 3][0];
    bf16x8 af[2], bfr[4];
#pragma unroll
    for (int mi = 0; mi < 2; ++mi) {
      const int rr = wm * 32 + mi * 16 + lr;
      const int cw = lg ^ ((rr >> 1) & 3);
      af[mi] = ld_frag16(Ab + rr * BK + cw * 8);
    }
#pragma unroll
    for (int ni = 0; ni < 4; ++ni) {
      const int cc = wn * 64 + ni * 16 + lr;
      bfr[ni] = ld_frag16(Bb + cc * SB + lg * 8);
    }
#pragma unroll
    for (int mi = 0; mi < 2; ++mi)
#pragma unroll
      for (int ni = 0; ni < 4; ++ni)
        acc[mi][ni] = __builtin_amdgcn_mfma_f32_16x16x32_bf16(
            af[mi], bfr[ni], acc[mi][ni], 0, 0, 0);
  };

  float vA[16], vB[16];   // even tiles -> vA, odd -> vB (static sets)

  // ---- prologue: tiles 0,1 in flight; publish B(0) ----
  ISSUE_A(0); LOAD_B(0, vA);
  ISSUE_A(1); LOAD_B(1, vB);
  WRITE_B(0, vA);            // vmcnt wait proves A(0) also landed
  bar_lds();

  // ---- main loop, unrolled by 2 for static vA/vB ping-pong ----
  for (int jj = 0; jj < NT / 2; ++jj) {
    const int j0 = 2 * jj;
    if (j0 + 2 < NT) { ISSUE_A(j0 + 2); LOAD_B(j0 + 2, vA); }
    WRITE_B(j0 + 1, vB);     // counted vmcnt: 17 newer ops stay in flight
    COMPUTE(j0);
    bar_lds();
    const int j1 = j0 + 1;
    if (j1 + 2 < NT) { ISSUE_A(j1 + 2); LOAD_B(j1 + 2, vB); }
    if (j1 + 1 < NT) WRITE_B(j1 + 1, vA);
    COMPUTE(j1);
    if (jj != NT / 2 - 1) bar_lds();
  }

  // ---- epilogue: bias + relu, fp32 store ----
#pragma unroll
  for (int mi = 0; mi < 2; ++mi) {
#pragma unroll
    for (int rr = 0; rr < 4; ++rr) {
      const int go = h * 128 + mh * 64 + wm * 32 + mi * 16 + lg * 4 + rr;
      const float bi = bias[go];
      float* orow = out + ((size_t)(b * 256 + go)) * Nn + n0;
#pragma unroll
      for (int ni = 0; ni < 4; ++ni) {
        const int col = wn * 64 + ni * 16 + lr;
        orow[col] = fmaxf(acc[mi][ni][rr] + bi, 0.f);
      }
    }
  }
}

extern "C" void kernel_launch(void* const* d_in, const int* in_sizes, int n_in,
                              void* d_out, int out_size, void* d_ws, size_t ws_size,
                              hipStream_t stream) {
  const float* x    = (const float*)d_in[0];
  const float* adj1 = (const float*)d_in[1];
  const float* adj2 = (const float*)d_in[2];
  const float* wgt  = (const float*)d_in[3];
  const float* bias = (const float*)d_in[4];
  float* out = (float*)d_out;
  u16* Y = (u16*)d_ws;   // 16*256*1024 bf16 = 8.4 MB

  dim3 g1(16, 2, 16);
  gemm1<<<g1, dim3(256), 0, stream>>>(x, wgt, Y);
  dim3 g2(4, 4, 16);   // n-tiles(256), h*2+mh, batch
  gemm2<<<g2, dim3(512), 0, stream>>>(adj1, adj2, Y, bias, out);
}

// Round 7
// 52.747 us; speedup vs baseline: 1.2545x; 1.2545x over previous
//
#include <hip/hip_runtime.h>
#include <hip/hip_bf16.h>

typedef unsigned short u16;
typedef unsigned int u32;
typedef __attribute__((ext_vector_type(8))) short bf16x8;
typedef __attribute__((ext_vector_type(4))) float f32x4;

__device__ __forceinline__ u16 f2bf(float f) {
  return __builtin_bit_cast(u16, __float2bfloat16(f));
}

__device__ __forceinline__ bf16x8 ld_frag16(const u16* p) {
  return __builtin_bit_cast(bf16x8, *reinterpret_cast<const uint4*>(p));
}

__device__ __forceinline__ void gload_lds16(const void* g, void* l) {
  __builtin_amdgcn_global_load_lds((const __attribute__((address_space(1))) void*)g,
                                   (__attribute__((address_space(3))) void*)l, 16, 0, 0);
}

// Barrier without vmcnt drain: publish LDS writes, fence scheduler, raw barrier.
__device__ __forceinline__ void bar_lds() {
  asm volatile("s_waitcnt lgkmcnt(0)" ::: "memory");
  __builtin_amdgcn_sched_barrier(0);
  __builtin_amdgcn_s_barrier();
}

// ---------------------------------------------------------------------------
// Kernel 1: Y[b] = bf16( W @ X[b] )   (unchanged)
// ---------------------------------------------------------------------------
__global__ __launch_bounds__(256, 3) void gemm1(
    const float* __restrict__ x, const float* __restrict__ weight,
    u16* __restrict__ Y)
{
  constexpr int Nn = 1024, K = 256, BK = 32, SB = 40;
  __shared__ __align__(16) u16 As[128 * 32];
  __shared__ __align__(16) u16 Bs[64 * SB];

  const int t = threadIdx.x;
  const int b = blockIdx.z, mt = blockIdx.y, n0 = blockIdx.x * 64;

  const float* Wp = weight + (size_t)mt * 128 * K;
  const float* Xb = x + (size_t)b * K * Nn;

  const int w = t >> 6, l = t & 63;
  const int wm = w >> 1, wn = w & 1;
  const int lr = l & 15, lg = l >> 4;

  const int ar = t >> 1, akc = (t & 1) * 16;
  const int bm = t & 63, bkq = t >> 6;
  const float* Xcol = Xb + n0 + bm;

  f32x4 acc[4][2] = {};

  for (int kt = 0; kt < K / BK; ++kt) {
    const int k0 = kt * BK;

    float4 a4[4];
#pragma unroll
    for (int uu = 0; uu < 4; ++uu)
      a4[uu] = reinterpret_cast<const float4*>(Wp + (size_t)ar * K + k0 + akc)[uu];
    union { uint4 q[2]; u16 s[16]; } ua;
#pragma unroll
    for (int uu = 0; uu < 4; ++uu) {
      ua.s[uu * 4 + 0] = f2bf(a4[uu].x); ua.s[uu * 4 + 1] = f2bf(a4[uu].y);
      ua.s[uu * 4 + 2] = f2bf(a4[uu].z); ua.s[uu * 4 + 3] = f2bf(a4[uu].w);
    }
    {
      const int c0 = akc >> 3;
      const int sw = (ar >> 1) & 3;
      uint4* Aq = reinterpret_cast<uint4*>(As);
      Aq[ar * 4 + ((c0 + 0) ^ sw)] = ua.q[0];
      Aq[ar * 4 + ((c0 + 1) ^ sw)] = ua.q[1];
    }

    float v[8];
#pragma unroll
    for (int j = 0; j < 8; ++j)
      v[j] = Xcol[(size_t)(k0 + bkq * 8 + j) * Nn];
    union { uint4 q; u16 s[8]; } ub;
#pragma unroll
    for (int j = 0; j < 8; ++j) ub.s[j] = f2bf(v[j]);
    reinterpret_cast<uint4*>(Bs)[bm * 5 + bkq] = ub.q;

    __syncthreads();

    bf16x8 af[4], bfr[2];
#pragma unroll
    for (int mi = 0; mi < 4; ++mi) {
      const int rr = wm * 64 + mi * 16 + lr;
      const int cw = lg ^ ((rr >> 1) & 3);
      af[mi] = ld_frag16(As + rr * BK + cw * 8);
    }
#pragma unroll
    for (int ni = 0; ni < 2; ++ni) {
      const int cc = wn * 32 + ni * 16 + lr;
      bfr[ni] = ld_frag16(Bs + cc * SB + lg * 8);
    }
#pragma unroll
    for (int mi = 0; mi < 4; ++mi)
#pragma unroll
      for (int ni = 0; ni < 2; ++ni)
        acc[mi][ni] = __builtin_amdgcn_mfma_f32_16x16x32_bf16(
            af[mi], bfr[ni], acc[mi][ni], 0, 0, 0);

    __syncthreads();
  }

#pragma unroll
  for (int mi = 0; mi < 4; ++mi) {
#pragma unroll
    for (int rr = 0; rr < 4; ++rr) {
      const int row = mt * 128 + wm * 64 + mi * 16 + lg * 4 + rr;
      u16* Yrow = Y + ((size_t)(b * 256 + row)) * Nn + n0;
#pragma unroll
      for (int ni = 0; ni < 2; ++ni) {
        const int col = wn * 32 + ni * 16 + lr;
        Yrow[col] = f2bf(acc[mi][ni][rr]);
      }
    }
  }
}

// ---------------------------------------------------------------------------
// Kernel 2 (v5): out = relu(Y_half @ adj_h + bias)
// BM=128, BN=128, BK=32. 256 blocks (8 n-tiles x 2 h x 16 b), 512 thr
// (8 waves, 2m x 4n; wave tile 64x32).
// adj staged ROW-WISE: pass1 reads contiguous 512B row-runs (1KB/wave-op),
// cvt bf16, write [k][n] LDS (stride 132). pass2 transposes in LDS to the
// proven [n][k] SB=40 fragment layout. 3-deep pipeline, distance-2 globals,
// counted vmcnt, ONE lgkm-barrier per iter.
// ---------------------------------------------------------------------------
__global__ __launch_bounds__(512, 2) void gemm2(
    const float* __restrict__ adj1, const float* __restrict__ adj2,
    const u16* __restrict__ Y, const float* __restrict__ bias,
    float* __restrict__ out)
{
  constexpr int Nn = 1024, BK = 32, NT = Nn / BK;
  constexpr int SB1 = 132;   // Bb row stride (elems): 128 + 4 pad
  constexpr int SB2 = 40;    // Bs2 row stride (elems)
  __shared__ __align__(16) u16 As[4][128 * 32];     // 4 x 8 KB
  __shared__ __align__(16) u16 Bb[2][32 * SB1];     // 2 x 8.25 KB  [k][n] bf16
  __shared__ __align__(16) u16 Bs2[2][128 * SB2];   // 2 x 10 KB    [n][k] bf16

  const int t = threadIdx.x;
  const int b = blockIdx.z, h = blockIdx.y, n0 = blockIdx.x * 128;

  const float* adj = (h == 0 ? adj1 : adj2) + (size_t)b * Nn * Nn;
  const u16* Yb = Y + ((size_t)(b * 256 + h * 128)) * Nn;  // [128][1024] bf16

  const int w = t >> 6, l = t & 63;
  const int wm = w >> 2, wn = w & 3;          // 2 m x 4 n waves
  const int lr = l & 15, lg = l >> 4;

  // ---- A staging (identical scheme to validated v3): chunk t of 512 ----
  const int a_r = t >> 2, a_c = t & 3;
  const int a_cg = a_c ^ ((a_r >> 1) & 3);
  const u16* a_src = Yb + (size_t)a_r * Nn + a_cg * 8;   // + tt*BK at use
  const int a_dstoff = (w * 64) * 8;                      // u16 elements

  // ---- B pass1: row-wise reads. load i: float4 f = i*512 + t ----
  // row = i*16 + (t>>5)  (0..31), cols n = 4*(t&31) .. +3
  const int b1r = t >> 5, b1c4 = t & 31;
  const float* bsrc0 = adj + (size_t)(0 * 16 + b1r) * Nn + n0 + 4 * b1c4;
  const float* bsrc1 = adj + (size_t)(1 * 16 + b1r) * Nn + n0 + 4 * b1c4;

  // ---- B pass2: thread owns col n = t>>2, k-quad kq = t&3 ----
  const int p2n = t >> 2, p2kq = t & 3;

  f32x4 acc[4][2] = {};

  auto ISSUE_A = [&](int tt) {
    gload_lds16(a_src + tt * BK, (void*)(&As[tt & 3][0] + a_dstoff));
  };
  auto LOAD_B = [&](int tt, float4* v) {
    v[0] = *reinterpret_cast<const float4*>(bsrc0 + (size_t)tt * BK * Nn);
    v[1] = *reinterpret_cast<const float4*>(bsrc1 + (size_t)tt * BK * Nn);
  };
  auto PASS1 = [&](int tt, const float4* v) {
#pragma unroll
    for (int i = 0; i < 2; ++i) {
      union { uint2 q; u16 s[4]; } ub;
      ub.s[0] = f2bf(v[i].x); ub.s[1] = f2bf(v[i].y);
      ub.s[2] = f2bf(v[i].z); ub.s[3] = f2bf(v[i].w);
      *reinterpret_cast<uint2*>(&Bb[tt & 1][0] + (i * 16 + b1r) * SB1 + 4 * b1c4) = ub.q;
    }
  };
  auto PASS2 = [&](int tt) {
    const u16* src = &Bb[tt & 1][0];
    union { uint4 q; u16 s[8]; } up;
#pragma unroll
    for (int j2 = 0; j2 < 8; ++j2)
      up.s[j2] = src[(p2kq * 8 + j2) * SB1 + p2n];
    *reinterpret_cast<uint4*>(&Bs2[tt & 1][0] + p2n * SB2 + p2kq * 8) = up.q;
  };
  auto COMPUTE = [&](int tt) {
    const u16* Ab = &As[tt & 3][0];
    const u16* Bbf = &Bs2[tt & 1][0];
    bf16x8 af[4], bfr[2];
#pragma unroll
    for (int mi = 0; mi < 4; ++mi) {
      const int rr = wm * 64 + mi * 16 + lr;
      const int cw = lg ^ ((rr >> 1) & 3);
      af[mi] = ld_frag16(Ab + rr * BK + cw * 8);
    }
#pragma unroll
    for (int ni = 0; ni < 2; ++ni) {
      const int cc = wn * 32 + ni * 16 + lr;
      bfr[ni] = ld_frag16(Bbf + cc * SB2 + lg * 8);
    }
#pragma unroll
    for (int mi = 0; mi < 4; ++mi)
#pragma unroll
      for (int ni = 0; ni < 2; ++ni)
        acc[mi][ni] = __builtin_amdgcn_mfma_f32_16x16x32_bf16(
            af[mi], bfr[ni], acc[mi][ni], 0, 0, 0);
  };

  float4 regA[2], regB[2];   // even-tile loads -> regA, odd -> regB

  // ---- prologue: tiles 0,1 issued; Bb[0] published ----
  ISSUE_A(0); LOAD_B(0, regA);
  ISSUE_A(1); LOAD_B(1, regB);
  PASS1(0, regA);            // vmcnt wait on regA also proves As[0] landed
  bar_lds();

  // ---- main loop (NT=32), unrolled x2 for static regA/regB ping-pong ----
  for (int jj = 0; jj < NT / 2; ++jj) {
    const int j0 = 2 * jj;
    if (j0 + 2 < NT) { ISSUE_A(j0 + 2); LOAD_B(j0 + 2, regA); }
    PASS1(j0 + 1, regB);     // counted vmcnt: this iter's 3 ops stay in flight
    PASS2(j0);
    bar_lds();
    COMPUTE(j0);

    const int j1 = j0 + 1;
    if (j1 + 2 < NT) { ISSUE_A(j1 + 2); LOAD_B(j1 + 2, regB); }
    if (j1 + 1 < NT) PASS1(j1 + 1, regA);
    PASS2(j1);
    bar_lds();
    COMPUTE(j1);
  }

  // ---- epilogue: bias + relu, fp32 store ----
#pragma unroll
  for (int mi = 0; mi < 4; ++mi) {
#pragma unroll
    for (int rr = 0; rr < 4; ++rr) {
      const int go = h * 128 + wm * 64 + mi * 16 + lg * 4 + rr;
      const float bi = bias[go];
      float* orow = out + ((size_t)(b * 256 + go)) * Nn + n0;
#pragma unroll
      for (int ni = 0; ni < 2; ++ni) {
        const int col = wn * 32 + ni * 16 + lr;
        orow[col] = fmaxf(acc[mi][ni][rr] + bi, 0.f);
      }
    }
  }
}

extern "C" void kernel_launch(void* const* d_in, const int* in_sizes, int n_in,
                              void* d_out, int out_size, void* d_ws, size_t ws_size,
                              hipStream_t stream) {
  const float* x    = (const float*)d_in[0];
  const float* adj1 = (const float*)d_in[1];
  const float* adj2 = (const float*)d_in[2];
  const float* wgt  = (const float*)d_in[3];
  const float* bias = (const float*)d_in[4];
  float* out = (float*)d_out;
  u16* Y = (u16*)d_ws;   // 16*256*1024 bf16 = 8.4 MB

  dim3 g1(16, 2, 16);
  gemm1<<<g1, dim3(256), 0, stream>>>(x, wgt, Y);
  dim3 g2(8, 2, 16);   // n-tiles(128), half, batch
  gemm2<<<g2, dim3(512), 0, stream>>>(adj1, adj2, Y, bias, out);
}

// Round 8
// 43.661 us; speedup vs baseline: 1.5156x; 1.2081x over previous
//
#include <hip/hip_runtime.h>
#include <hip/hip_bf16.h>

typedef unsigned short u16;
typedef unsigned int u32;
typedef __attribute__((ext_vector_type(8))) short bf16x8;
typedef __attribute__((ext_vector_type(4))) float f32x4;

__device__ __forceinline__ u16 f2bf(float f) {
  return __builtin_bit_cast(u16, __float2bfloat16(f));
}

__device__ __forceinline__ bf16x8 ld_frag16(const u16* p) {
  return __builtin_bit_cast(bf16x8, *reinterpret_cast<const uint4*>(p));
}

__device__ __forceinline__ void gload_lds16(const void* g, void* l) {
  __builtin_amdgcn_global_load_lds((const __attribute__((address_space(1))) void*)g,
                                   (__attribute__((address_space(3))) void*)l, 16, 0, 0);
}

// Barrier without vmcnt drain: publish LDS writes, fence scheduler, raw barrier.
__device__ __forceinline__ void bar_lds() {
  asm volatile("s_waitcnt lgkmcnt(0)" ::: "memory");
  __builtin_amdgcn_sched_barrier(0);
  __builtin_amdgcn_s_barrier();
}

// ---------------------------------------------------------------------------
// Kernel 1: Y[b] = bf16( W @ X[b] )   (unchanged)
// ---------------------------------------------------------------------------
__global__ __launch_bounds__(256, 3) void gemm1(
    const float* __restrict__ x, const float* __restrict__ weight,
    u16* __restrict__ Y)
{
  constexpr int Nn = 1024, K = 256, BK = 32, SB = 40;
  __shared__ __align__(16) u16 As[128 * 32];
  __shared__ __align__(16) u16 Bs[64 * SB];

  const int t = threadIdx.x;
  const int b = blockIdx.z, mt = blockIdx.y, n0 = blockIdx.x * 64;

  const float* Wp = weight + (size_t)mt * 128 * K;
  const float* Xb = x + (size_t)b * K * Nn;

  const int w = t >> 6, l = t & 63;
  const int wm = w >> 1, wn = w & 1;
  const int lr = l & 15, lg = l >> 4;

  const int ar = t >> 1, akc = (t & 1) * 16;
  const int bm = t & 63, bkq = t >> 6;
  const float* Xcol = Xb + n0 + bm;

  f32x4 acc[4][2] = {};

  for (int kt = 0; kt < K / BK; ++kt) {
    const int k0 = kt * BK;

    float4 a4[4];
#pragma unroll
    for (int uu = 0; uu < 4; ++uu)
      a4[uu] = reinterpret_cast<const float4*>(Wp + (size_t)ar * K + k0 + akc)[uu];
    union { uint4 q[2]; u16 s[16]; } ua;
#pragma unroll
    for (int uu = 0; uu < 4; ++uu) {
      ua.s[uu * 4 + 0] = f2bf(a4[uu].x); ua.s[uu * 4 + 1] = f2bf(a4[uu].y);
      ua.s[uu * 4 + 2] = f2bf(a4[uu].z); ua.s[uu * 4 + 3] = f2bf(a4[uu].w);
    }
    {
      const int c0 = akc >> 3;
      const int sw = (ar >> 1) & 3;
      uint4* Aq = reinterpret_cast<uint4*>(As);
      Aq[ar * 4 + ((c0 + 0) ^ sw)] = ua.q[0];
      Aq[ar * 4 + ((c0 + 1) ^ sw)] = ua.q[1];
    }

    float v[8];
#pragma unroll
    for (int j = 0; j < 8; ++j)
      v[j] = Xcol[(size_t)(k0 + bkq * 8 + j) * Nn];
    union { uint4 q; u16 s[8]; } ub;
#pragma unroll
    for (int j = 0; j < 8; ++j) ub.s[j] = f2bf(v[j]);
    reinterpret_cast<uint4*>(Bs)[bm * 5 + bkq] = ub.q;

    __syncthreads();

    bf16x8 af[4], bfr[2];
#pragma unroll
    for (int mi = 0; mi < 4; ++mi) {
      const int rr = wm * 64 + mi * 16 + lr;
      const int cw = lg ^ ((rr >> 1) & 3);
      af[mi] = ld_frag16(As + rr * BK + cw * 8);
    }
#pragma unroll
    for (int ni = 0; ni < 2; ++ni) {
      const int cc = wn * 32 + ni * 16 + lr;
      bfr[ni] = ld_frag16(Bs + cc * SB + lg * 8);
    }
#pragma unroll
    for (int mi = 0; mi < 4; ++mi)
#pragma unroll
      for (int ni = 0; ni < 2; ++ni)
        acc[mi][ni] = __builtin_amdgcn_mfma_f32_16x16x32_bf16(
            af[mi], bfr[ni], acc[mi][ni], 0, 0, 0);

    __syncthreads();
  }

#pragma unroll
  for (int mi = 0; mi < 4; ++mi) {
#pragma unroll
    for (int rr = 0; rr < 4; ++rr) {
      const int row = mt * 128 + wm * 64 + mi * 16 + lg * 4 + rr;
      u16* Yrow = Y + ((size_t)(b * 256 + row)) * Nn + n0;
#pragma unroll
      for (int ni = 0; ni < 2; ++ni) {
        const int col = wn * 32 + ni * 16 + lr;
        Yrow[col] = f2bf(acc[mi][ni][rr]);
      }
    }
  }
}

// ---------------------------------------------------------------------------
// Kernel 2 (v6 = v5 + XCD clustering): out = relu(Y_half @ adj_h + bias)
// BM=128, BN=128, BK=32. 256 blocks, 512 thr (8 waves, 2m x 4n).
// CHANGE vs v5: 1-D grid; the 8 n-tile blocks of one (b,h) pair are placed
// on the SAME XCD (bid = xcd + 8*nt + 64*pg, xcd = pair&7) so their 512B
// row-strips merge into full 4KB sequential rows in the XCD's L2 miss
// stream (DRAM page-efficiency test). Everything else byte-identical.
// ---------------------------------------------------------------------------
__global__ __launch_bounds__(512, 2) void gemm2(
    const float* __restrict__ adj1, const float* __restrict__ adj2,
    const u16* __restrict__ Y, const float* __restrict__ bias,
    float* __restrict__ out)
{
  constexpr int Nn = 1024, BK = 32, NT = Nn / BK;
  constexpr int SB1 = 132;   // Bb row stride (elems): 128 + 4 pad
  constexpr int SB2 = 40;    // Bs2 row stride (elems)
  __shared__ __align__(16) u16 As[4][128 * 32];     // 4 x 8 KB
  __shared__ __align__(16) u16 Bb[2][32 * SB1];     // 2 x 8.25 KB  [k][n] bf16
  __shared__ __align__(16) u16 Bs2[2][128 * SB2];   // 2 x 10 KB    [n][k] bf16

  const int t = threadIdx.x;

  // XCD-clustered decode: pair p's 8 n-tile blocks all have bid%8 == p&7.
  const int bid = blockIdx.x;
  const int xcd = bid & 7;
  const int nt  = (bid >> 3) & 7;
  const int pg  = bid >> 6;
  const int p   = xcd + pg * 8;    // 0..31
  const int b   = p >> 1, h = p & 1;
  const int n0  = nt * 128;

  const float* adj = (h == 0 ? adj1 : adj2) + (size_t)b * Nn * Nn;
  const u16* Yb = Y + ((size_t)(b * 256 + h * 128)) * Nn;  // [128][1024] bf16

  const int w = t >> 6, l = t & 63;
  const int wm = w >> 2, wn = w & 3;          // 2 m x 4 n waves
  const int lr = l & 15, lg = l >> 4;

  // ---- A staging (validated): chunk t of 512, source-swizzled ----
  const int a_r = t >> 2, a_c = t & 3;
  const int a_cg = a_c ^ ((a_r >> 1) & 3);
  const u16* a_src = Yb + (size_t)a_r * Nn + a_cg * 8;   // + tt*BK at use
  const int a_dstoff = (w * 64) * 8;                      // u16 elements

  // ---- B pass1: row-wise contiguous reads ----
  const int b1r = t >> 5, b1c4 = t & 31;
  const float* bsrc0 = adj + (size_t)(0 * 16 + b1r) * Nn + n0 + 4 * b1c4;
  const float* bsrc1 = adj + (size_t)(1 * 16 + b1r) * Nn + n0 + 4 * b1c4;

  // ---- B pass2: thread owns col n = t>>2, k-quad kq = t&3 ----
  const int p2n = t >> 2, p2kq = t & 3;

  f32x4 acc[4][2] = {};

  auto ISSUE_A = [&](int tt) {
    gload_lds16(a_src + tt * BK, (void*)(&As[tt & 3][0] + a_dstoff));
  };
  auto LOAD_B = [&](int tt, float4* v) {
    v[0] = *reinterpret_cast<const float4*>(bsrc0 + (size_t)tt * BK * Nn);
    v[1] = *reinterpret_cast<const float4*>(bsrc1 + (size_t)tt * BK * Nn);
  };
  auto PASS1 = [&](int tt, const float4* v) {
#pragma unroll
    for (int i = 0; i < 2; ++i) {
      union { uint2 q; u16 s[4]; } ub;
      ub.s[0] = f2bf(v[i].x); ub.s[1] = f2bf(v[i].y);
      ub.s[2] = f2bf(v[i].z); ub.s[3] = f2bf(v[i].w);
      *reinterpret_cast<uint2*>(&Bb[tt & 1][0] + (i * 16 + b1r) * SB1 + 4 * b1c4) = ub.q;
    }
  };
  auto PASS2 = [&](int tt) {
    const u16* src = &Bb[tt & 1][0];
    union { uint4 q; u16 s[8]; } up;
#pragma unroll
    for (int j2 = 0; j2 < 8; ++j2)
      up.s[j2] = src[(p2kq * 8 + j2) * SB1 + p2n];
    *reinterpret_cast<uint4*>(&Bs2[tt & 1][0] + p2n * SB2 + p2kq * 8) = up.q;
  };
  auto COMPUTE = [&](int tt) {
    const u16* Ab = &As[tt & 3][0];
    const u16* Bbf = &Bs2[tt & 1][0];
    bf16x8 af[4], bfr[2];
#pragma unroll
    for (int mi = 0; mi < 4; ++mi) {
      const int rr = wm * 64 + mi * 16 + lr;
      const int cw = lg ^ ((rr >> 1) & 3);
      af[mi] = ld_frag16(Ab + rr * BK + cw * 8);
    }
#pragma unroll
    for (int ni = 0; ni < 2; ++ni) {
      const int cc = wn * 32 + ni * 16 + lr;
      bfr[ni] = ld_frag16(Bbf + cc * SB2 + lg * 8);
    }
#pragma unroll
    for (int mi = 0; mi < 4; ++mi)
#pragma unroll
      for (int ni = 0; ni < 2; ++ni)
        acc[mi][ni] = __builtin_amdgcn_mfma_f32_16x16x32_bf16(
            af[mi], bfr[ni], acc[mi][ni], 0, 0, 0);
  };

  float4 regA[2], regB[2];   // even-tile loads -> regA, odd -> regB

  // ---- prologue: tiles 0,1 issued; Bb[0] published ----
  ISSUE_A(0); LOAD_B(0, regA);
  ISSUE_A(1); LOAD_B(1, regB);
  PASS1(0, regA);            // vmcnt wait on regA also proves As[0] landed
  bar_lds();

  // ---- main loop (NT=32), unrolled x2 for static regA/regB ping-pong ----
  for (int jj = 0; jj < NT / 2; ++jj) {
    const int j0 = 2 * jj;
    if (j0 + 2 < NT) { ISSUE_A(j0 + 2); LOAD_B(j0 + 2, regA); }
    PASS1(j0 + 1, regB);     // counted vmcnt: newer ops stay in flight
    PASS2(j0);
    bar_lds();
    COMPUTE(j0);

    const int j1 = j0 + 1;
    if (j1 + 2 < NT) { ISSUE_A(j1 + 2); LOAD_B(j1 + 2, regB); }
    if (j1 + 1 < NT) PASS1(j1 + 1, regA);
    PASS2(j1);
    bar_lds();
    COMPUTE(j1);
  }

  // ---- epilogue: bias + relu, fp32 store ----
#pragma unroll
  for (int mi = 0; mi < 4; ++mi) {
#pragma unroll
    for (int rr = 0; rr < 4; ++rr) {
      const int go = h * 128 + wm * 64 + mi * 16 + lg * 4 + rr;
      const float bi = bias[go];
      float* orow = out + ((size_t)(b * 256 + go)) * Nn + n0;
#pragma unroll
      for (int ni = 0; ni < 2; ++ni) {
        const int col = wn * 32 + ni * 16 + lr;
        orow[col] = fmaxf(acc[mi][ni][rr] + bi, 0.f);
      }
    }
  }
}

extern "C" void kernel_launch(void* const* d_in, const int* in_sizes, int n_in,
                              void* d_out, int out_size, void* d_ws, size_t ws_size,
                              hipStream_t stream) {
  const float* x    = (const float*)d_in[0];
  const float* adj1 = (const float*)d_in[1];
  const float* adj2 = (const float*)d_in[2];
  const float* wgt  = (const float*)d_in[3];
  const float* bias = (const float*)d_in[4];
  float* out = (float*)d_out;
  u16* Y = (u16*)d_ws;   // 16*256*1024 bf16 = 8.4 MB

  dim3 g1(16, 2, 16);
  gemm1<<<g1, dim3(256), 0, stream>>>(x, wgt, Y);
  gemm2<<<dim3(256), dim3(512), 0, stream>>>(adj1, adj2, Y, bias, out);
}